// Round 12
// baseline (214.346 us; speedup 1.0000x reference)
//
#include <hip/hip_runtime.h>
#include <cstdint>
#include <cstddef>

// ---------------------------------------------------------------------------
// SelfAttentionLayer: x[32,256,4096] f32; Wq/Wk/Wv[256,256], bq/bk/bv[256]
//   G_b = X_b X_b^T,  r_b = X_b 1
//   S_b = Wq G Wk^T + (Wq r) bk^T + bq (Wk r)^T + N bq bk^T, scaled 1/64
//   W_b = softmax_rows(S_b);  M_b = W_b Wv;  c_b = W_b bv
//   out_b = M_b X_b + c_b 1^T
// R11 = R10 (best, 178us) + gram at 16 splits (K=256, grid 512 = 2 blocks/CU
// so rotation decorrelates WITHIN a CU) + merged weight-convert kernel.
// Traffic cost: Gpart 32->64MB; predicted net win from gram BW uplift.
// Failed structures (do not retry): R4 scattered small stores, R6 fused xbt,
// R7 16-wave blocks, R8 direct-global-MFMA k_out.
// ---------------------------------------------------------------------------

typedef float f32x4 __attribute__((ext_vector_type(4)));
typedef __bf16 bf16x8 __attribute__((ext_vector_type(8)));
typedef unsigned short u16;
typedef u16 u16x8 __attribute__((ext_vector_type(8)));
typedef u16 u16x4 __attribute__((ext_vector_type(4)));

__device__ __forceinline__ u16 f2bf(float f) {
    unsigned u = __builtin_bit_cast(unsigned, f);
    u += 0x7FFFu + ((u >> 16) & 1u);   // RNE
    return (u16)(u >> 16);
}
__device__ __forceinline__ float bf2f(u16 h) {
    unsigned u = ((unsigned)h) << 16;
    return __builtin_bit_cast(float, u);
}
__device__ __forceinline__ f32x4 mfma16(bf16x8 a, bf16x8 b, f32x4 c) {
    return __builtin_amdgcn_mfma_f32_16x16x32_bf16(a, b, c, 0, 0, 0);
}

// ---------------------------------------------------------------------------
// K0: merged weight converts. grid 96 x 256 thr.
//   blocks 0..31:  Wq -> Wqb (bf16)
//   blocks 32..63: Wk -> Wkb (bf16)
//   blocks 64..95: Wv -> WvT (bf16, transposed [c][e])
// ---------------------------------------------------------------------------
__global__ void k_wcvt3(const float* __restrict__ Wq, const float* __restrict__ Wk,
                        const float* __restrict__ Wv,
                        u16* __restrict__ Wqb, u16* __restrict__ Wkb,
                        u16* __restrict__ WvT) {
    const int m = blockIdx.x >> 5, sub = blockIdx.x & 31;
    if (m < 2) {
        const float* src = m == 0 ? Wq : Wk;
        u16* dst = m == 0 ? Wqb : Wkb;
        const int i = sub * 2048 + threadIdx.x * 8;
        f32x4 w0 = *(const f32x4*)(src + i);
        f32x4 w1 = *(const f32x4*)(src + i + 4);
        u16x8 pk;
        pk[0] = f2bf(w0[0]); pk[1] = f2bf(w0[1]); pk[2] = f2bf(w0[2]); pk[3] = f2bf(w0[3]);
        pk[4] = f2bf(w1[0]); pk[5] = f2bf(w1[1]); pk[6] = f2bf(w1[2]); pk[7] = f2bf(w1[3]);
        *(u16x8*)&dst[i] = pk;
    } else {
        const int eb = sub;            // e-base = eb*8
        const int c  = threadIdx.x;
        u16x8 pk;
#pragma unroll
        for (int j = 0; j < 8; ++j) pk[j] = f2bf(Wv[(eb * 8 + j) * 256 + c]);
        *(u16x8*)&WvT[c * 256 + eb * 8] = pk;
    }
}

// ---------------------------------------------------------------------------
// K1: pipelined Gram partials, 16 K-splits (K=256, 4 chunks of 64n).
// grid = 32 b x 16 splits = 512 blocks (2/CU), 512 thr.  Rotation rot=blk&3.
// bf16 flush (proven safe pattern); rowsums non-atomic to rsp.
// ---------------------------------------------------------------------------
__global__ __launch_bounds__(512, 2) void k_gram_b(const float* __restrict__ x,
                                                   u16* __restrict__ Gpart,
                                                   float* __restrict__ rsp) {
    __shared__ __align__(16) u16 lds[2][256 * 64];
    const int b = blockIdx.x >> 4, split = blockIdx.x & 15;
    const int rot = blockIdx.x & 3;
    const int t = threadIdx.x;
    const int lane = t & 63, wid = t >> 6;
    const int g = lane >> 4, q = lane & 15;

    f32x4 zero4 = {0.f, 0.f, 0.f, 0.f};
    f32x4 acc[2][16];
#pragma unroll
    for (int i = 0; i < 2; ++i)
#pragma unroll
        for (int j = 0; j < 16; ++j) acc[i][j] = zero4;

    const int c_st = t >> 1, half = t & 1;
    const int swz_w = (c_st & 7) << 3;
    const float* xp = x + ((size_t)b * 256 + c_st) * 4096 + split * 256 + half * 32;

    float s = 0.f;
    f32x4 R[8];
    // preload + stage chunk `rot`
#pragma unroll
    for (int j = 0; j < 8; ++j) R[j] = *(const f32x4*)(xp + rot * 64 + j * 4);
#pragma unroll
    for (int kk = 0; kk < 4; ++kk) {
        f32x4 w0 = R[2 * kk], w1 = R[2 * kk + 1];
        s += w0[0] + w0[1] + w0[2] + w0[3] + w1[0] + w1[1] + w1[2] + w1[3];
        u16x8 pk;
        pk[0] = f2bf(w0[0]); pk[1] = f2bf(w0[1]); pk[2] = f2bf(w0[2]); pk[3] = f2bf(w0[3]);
        pk[4] = f2bf(w1[0]); pk[5] = f2bf(w1[1]); pk[6] = f2bf(w1[2]); pk[7] = f2bf(w1[3]);
        *(u16x8*)&lds[0][(c_st * 64 + half * 32 + kk * 8) ^ swz_w] = pk;
    }
    __syncthreads();

    for (int nc = 0; nc < 4; ++nc) {
        const int cur = nc & 1;
        if (nc < 3) {
            const int nxt = (nc + 1 + rot) & 3;
#pragma unroll
            for (int j = 0; j < 8; ++j) R[j] = *(const f32x4*)(xp + nxt * 64 + j * 4);
        }
#pragma unroll
        for (int ks = 0; ks < 2; ++ks) {
            const int c0 = 32 * wid + q;
            const int c1 = c0 + 16;
            bf16x8 a0 = *(const bf16x8*)&lds[cur][(c0 * 64 + ks * 32 + g * 8) ^ ((c0 & 7) << 3)];
            bf16x8 a1 = *(const bf16x8*)&lds[cur][(c1 * 64 + ks * 32 + g * 8) ^ ((c1 & 7) << 3)];
#pragma unroll
            for (int et = 0; et < 16; ++et) {
                const int c2 = et * 16 + q;
                bf16x8 bb = *(const bf16x8*)&lds[cur][(c2 * 64 + ks * 32 + g * 8) ^ ((c2 & 7) << 3)];
                acc[0][et] = mfma16(a0, bb, acc[0][et]);
                acc[1][et] = mfma16(a1, bb, acc[1][et]);
            }
        }
        if (nc < 3) {
#pragma unroll
            for (int kk = 0; kk < 4; ++kk) {
                f32x4 w0 = R[2 * kk], w1 = R[2 * kk + 1];
                s += w0[0] + w0[1] + w0[2] + w0[3] + w1[0] + w1[1] + w1[2] + w1[3];
                u16x8 pk;
                pk[0] = f2bf(w0[0]); pk[1] = f2bf(w0[1]); pk[2] = f2bf(w0[2]); pk[3] = f2bf(w0[3]);
                pk[4] = f2bf(w1[0]); pk[5] = f2bf(w1[1]); pk[6] = f2bf(w1[2]); pk[7] = f2bf(w1[3]);
                *(u16x8*)&lds[cur ^ 1][(c_st * 64 + half * 32 + kk * 8) ^ swz_w] = pk;
            }
        }
        __syncthreads();
    }

    // non-atomic rowsum partial (block owns its slice)
    rsp[(size_t)(split * 32 + b) * 512 + t] = s;

    // bf16 partial flush, safe q-in-column pattern (R7/R9-proven)
    u16* gp = Gpart + (size_t)(split * 32 + b) * 65536;
#pragma unroll
    for (int dt = 0; dt < 2; ++dt)
#pragma unroll
        for (int et = 0; et < 16; ++et)
#pragma unroll
            for (int rr = 0; rr < 4; ++rr) {
                const int cc = 32 * wid + dt * 16 + 4 * g + rr;
                gp[cc * 256 + et * 16 + q] = f2bf(acc[dt][et][rr]);
            }
}

// ---------------------------------------------------------------------------
// K2: Gb[j] = bf16( sum over 16 bf16 partials ).  grid 1024 x 256.
// ---------------------------------------------------------------------------
__global__ void k_reduce_b(const u16* __restrict__ Gpart, u16* __restrict__ Gb) {
    const size_t j = ((size_t)blockIdx.x * 256 + threadIdx.x) * 8;
    float s[8];
#pragma unroll
    for (int i = 0; i < 8; ++i) s[i] = 0.f;
#pragma unroll
    for (int sp = 0; sp < 16; ++sp) {
        u16x8 v = *(const u16x8*)(Gpart + (size_t)sp * 2097152 + j);
#pragma unroll
        for (int i = 0; i < 8; ++i) s[i] += bf2f(v[i]);
    }
    u16x8 pk;
#pragma unroll
    for (int i = 0; i < 8; ++i) pk[i] = f2bf(s[i]);
    *(u16x8*)&Gb[j] = pk;
}

// ---------------------------------------------------------------------------
// K3: T^T[e][c] = sum_c' G[c,c'] Wk[e,c'].  grid = 32 b x 8 e-tiles of 32.
// ---------------------------------------------------------------------------
__global__ __launch_bounds__(512, 4) void k_T(const u16* __restrict__ Gb,
                                              const u16* __restrict__ Wkb,
                                              u16* __restrict__ Tws) {
    const int b = blockIdx.x >> 3, ebase = (blockIdx.x & 7) * 32;
    const int t = threadIdx.x;
    const int lane = t & 63, wid = t >> 6;
    const int g = lane >> 4, q = lane & 15;

    f32x4 zero4 = {0.f, 0.f, 0.f, 0.f};
    f32x4 acc[2][2];
#pragma unroll
    for (int i = 0; i < 2; ++i)
#pragma unroll
        for (int j = 0; j < 2; ++j) acc[i][j] = zero4;

    const u16* gp = Gb + (size_t)b * 65536;
#pragma unroll
    for (int ks = 0; ks < 8; ++ks) {
        bf16x8 a0 = *(const bf16x8*)&gp[(32 * wid + q) * 256 + ks * 32 + g * 8];
        bf16x8 a1 = *(const bf16x8*)&gp[(32 * wid + 16 + q) * 256 + ks * 32 + g * 8];
        bf16x8 b0 = *(const bf16x8*)&Wkb[(ebase + q) * 256 + ks * 32 + g * 8];
        bf16x8 b1 = *(const bf16x8*)&Wkb[(ebase + 16 + q) * 256 + ks * 32 + g * 8];
        acc[0][0] = mfma16(a0, b0, acc[0][0]);
        acc[0][1] = mfma16(a0, b1, acc[0][1]);
        acc[1][0] = mfma16(a1, b0, acc[1][0]);
        acc[1][1] = mfma16(a1, b1, acc[1][1]);
    }
#pragma unroll
    for (int dt = 0; dt < 2; ++dt)
#pragma unroll
        for (int etl = 0; etl < 2; ++etl) {
            const int e = ebase + etl * 16 + q;
            const int cb = 32 * wid + dt * 16 + 4 * g;
            u16x4 pk;
            pk[0] = f2bf(acc[dt][etl][0]); pk[1] = f2bf(acc[dt][etl][1]);
            pk[2] = f2bf(acc[dt][etl][2]); pk[3] = f2bf(acc[dt][etl][3]);
            *(u16x4*)&Tws[((size_t)b * 256 + e) * 256 + cb] = pk;
        }
}

// ---------------------------------------------------------------------------
// K4: S^T -> softmax -> M^T.  grid = 32 b x 4 d-tiles of 64.  256 thr.
// Rowsum r_ summed from 16 non-atomic split partials (rsp).
// ---------------------------------------------------------------------------
__global__ __launch_bounds__(256, 2) void k_SWM(
    const u16* __restrict__ Tws, const float* __restrict__ rsp,
    const float* __restrict__ Wq, const u16* __restrict__ Wqb,
    const float* __restrict__ Wk,
    const float* __restrict__ bqv, const float* __restrict__ bkv,
    const float* __restrict__ bvv,
    const u16* __restrict__ WvT, u16* __restrict__ Mws, float* __restrict__ cpv) {
    __shared__ __align__(16) u16 Wlds[64 * 256];
    __shared__ float r_[256], v_[256], bk_[256], bv_[256], u_[64], bq_[64];
    const int b = blockIdx.x >> 2, dbase = (blockIdx.x & 3) * 64;
    const int t = threadIdx.x;
    const int lane = t & 63, wid = t >> 6;
    const int g = lane >> 4, q = lane & 15;

    {
        float sr = 0.f;
#pragma unroll
        for (int sp = 0; sp < 16; ++sp) {
            const float* rp = rsp + (size_t)(sp * 32 + b) * 512;
            sr += rp[2 * t] + rp[2 * t + 1];
        }
        r_[t] = sr;
    }
    bk_[t] = bkv[t];
    bv_[t] = bvv[t];
    if (t < 64) bq_[t] = bqv[dbase + t];
    __syncthreads();

    {
        float s = 0.f; const float* wp = Wk + (size_t)t * 256;
#pragma unroll 4
        for (int c = 0; c < 256; c += 4) {
            f32x4 w = *(const f32x4*)(wp + c);
            f32x4 rr = *(const f32x4*)(&r_[c]);
            s += w[0] * rr[0] + w[1] * rr[1] + w[2] * rr[2] + w[3] * rr[3];
        }
        v_[t] = s;
    }
    if (t < 64) {
        float s = 0.f; const float* wp = Wq + (size_t)(dbase + t) * 256;
#pragma unroll 4
        for (int c = 0; c < 256; c += 4) {
            f32x4 w = *(const f32x4*)(wp + c);
            f32x4 rr = *(const f32x4*)(&r_[c]);
            s += w[0] * rr[0] + w[1] * rr[1] + w[2] * rr[2] + w[3] * rr[3];
        }
        u_[t] = s;
    }
    __syncthreads();

    f32x4 zero4 = {0.f, 0.f, 0.f, 0.f};
    f32x4 acc[16];
#pragma unroll
    for (int j = 0; j < 16; ++j) acc[j] = zero4;

    const u16* tp = Tws + (size_t)b * 65536;
    const int d_l = wid * 16 + q;
#pragma unroll 2
    for (int ks = 0; ks < 8; ++ks) {
        bf16x8 bb = *(const bf16x8*)&Wqb[(dbase + d_l) * 256 + ks * 32 + g * 8];
#pragma unroll
        for (int et = 0; et < 16; ++et) {
            bf16x8 aa = *(const bf16x8*)&tp[(et * 16 + q) * 256 + ks * 32 + g * 8];
            acc[et] = mfma16(aa, bb, acc[et]);
        }
    }

    {
        const float ud = u_[d_l], bqd = bq_[d_l];
        float m = -3.4e38f;
#pragma unroll
        for (int et = 0; et < 16; ++et)
#pragma unroll
            for (int rr = 0; rr < 4; ++rr) {
                const int e = et * 16 + 4 * g + rr;
                float s = (acc[et][rr] + ud * bk_[e] + bqd * v_[e] + 4096.f * bqd * bk_[e]) * 0.015625f;
                acc[et][rr] = s;
                m = fmaxf(m, s);
            }
        m = fmaxf(m, __shfl_xor(m, 16));
        m = fmaxf(m, __shfl_xor(m, 32));
        float lsum = 0.f;
#pragma unroll
        for (int et = 0; et < 16; ++et)
#pragma unroll
            for (int rr = 0; rr < 4; ++rr) {
                float p = __expf(acc[et][rr] - m);
                acc[et][rr] = p;
                lsum += p;
            }
        lsum += __shfl_xor(lsum, 16);
        lsum += __shfl_xor(lsum, 32);
        const float inv = 1.f / lsum;
        float cp = 0.f;
#pragma unroll
        for (int et = 0; et < 16; ++et)
#pragma unroll
            for (int rr = 0; rr < 4; ++rr) {
                const int e = et * 16 + 4 * g + rr;
                float w = acc[et][rr] * inv;
                acc[et][rr] = w;
                cp += w * bv_[e];
            }
        cp += __shfl_xor(cp, 16);
        cp += __shfl_xor(cp, 32);
        if (g == 0) cpv[b * 256 + dbase + d_l] = cp;
    }

#pragma unroll
    for (int et = 0; et < 16; ++et) {
        u16x4 pk;
        pk[0] = f2bf(acc[et][0]); pk[1] = f2bf(acc[et][1]);
        pk[2] = f2bf(acc[et][2]); pk[3] = f2bf(acc[et][3]);
        *(u16x4*)&Wlds[(d_l * 256 + et * 16 + 4 * g) ^ ((d_l & 7) << 3)] = pk;
    }
    __syncthreads();

    f32x4 acc2[4][4];
#pragma unroll
    for (int i = 0; i < 4; ++i)
#pragma unroll
        for (int j = 0; j < 4; ++j) acc2[i][j] = zero4;

#pragma unroll 2
    for (int ks = 0; ks < 8; ++ks) {
        bf16x8 afr[4], bfr[4];
#pragma unroll
        for (int ct = 0; ct < 4; ++ct)
            afr[ct] = *(const bf16x8*)&WvT[(64 * wid + ct * 16 + q) * 256 + ks * 32 + g * 8];
#pragma unroll
        for (int j = 0; j < 4; ++j) {
            const int dl = j * 16 + q;
            bfr[j] = *(const bf16x8*)&Wlds[(dl * 256 + ks * 32 + g * 8) ^ ((dl & 7) << 3)];
        }
#pragma unroll
        for (int ct = 0; ct < 4; ++ct)
#pragma unroll
            for (int j = 0; j < 4; ++j)
                acc2[ct][j] = mfma16(afr[ct], bfr[j], acc2[ct][j]);
    }
#pragma unroll
    for (int ct = 0; ct < 4; ++ct)
#pragma unroll
        for (int j = 0; j < 4; ++j) {
            const int d = dbase + j * 16 + q;
            const int cb = 64 * wid + ct * 16 + 4 * g;
            u16x4 pk;
            pk[0] = f2bf(acc2[ct][j][0]); pk[1] = f2bf(acc2[ct][j][1]);
            pk[2] = f2bf(acc2[ct][j][2]); pk[3] = f2bf(acc2[ct][j][3]);
            *(u16x4*)&Mws[((size_t)b * 256 + d) * 256 + cb] = pk;
        }
}

// ---------------------------------------------------------------------------
// K5: out = M X + c 1^T.  grid = 32 b x 16 n-tiles, 512 thr.  R10 structure
// (rotated c-chunk order, plain stores).
// ---------------------------------------------------------------------------
__global__ __launch_bounds__(512, 2) void k_out(const float* __restrict__ x,
                                                const u16* __restrict__ Mws,
                                                const float* __restrict__ cpv,
                                                float* __restrict__ out) {
    __shared__ __align__(16) u16 xt[2][256 * 64];
    __shared__ float cp_l[256];
    const int b = blockIdx.x >> 4, nt = blockIdx.x & 15;
    const int rot = blockIdx.x & 3;
    const int n0 = nt * 256;
    const int t = threadIdx.x;
    const int lane = t & 63, wid = t >> 6;
    const int g = lane >> 4, q = lane & 15;

    if (t < 256) cp_l[t] = cpv[b * 256 + t];

    f32x4 zero4 = {0.f, 0.f, 0.f, 0.f};
    f32x4 acc[2][16];
#pragma unroll
    for (int i = 0; i < 2; ++i)
#pragma unroll
        for (int j = 0; j < 16; ++j) acc[i][j] = zero4;

    const int c8 = t & 7;
    const int n4 = t >> 3;
    const float* xbase = x + (size_t)b * 256 * 4096 + n0 + n4 * 4;
    const u16* mp = Mws + (size_t)b * 65536;

    f32x4 R[2][4];
    // preload + stage chunk `rot`
#pragma unroll
    for (int sub = 0; sub < 2; ++sub) {
        const int cc0 = rot * 64 + (c8 + 8 * sub) * 4;
#pragma unroll
        for (int j = 0; j < 4; ++j)
            R[sub][j] = *(const f32x4*)(xbase + (size_t)(cc0 + j) * 4096);
    }
#pragma unroll
    for (int sub = 0; sub < 2; ++sub)
#pragma unroll
        for (int j = 0; j < 4; ++j) {
            const int n = n4 * 4 + j;
            u16x4 pk;
            pk[0] = f2bf(R[sub][0][j]); pk[1] = f2bf(R[sub][1][j]);
            pk[2] = f2bf(R[sub][2][j]); pk[3] = f2bf(R[sub][3][j]);
            *(u16x4*)&xt[0][(n * 64 + (c8 + 8 * sub) * 4) ^ ((n & 7) << 3)] = pk;
        }
    __syncthreads();

    for (int ci = 0; ci < 4; ++ci) {
        const int cur = ci & 1;
        const int cc = (ci + rot) & 3;          // chunk being computed
        if (ci < 3) {
            const int nxt = (ci + 1 + rot) & 3; // chunk being prefetched
#pragma unroll
            for (int sub = 0; sub < 2; ++sub) {
                const int cc0 = nxt * 64 + (c8 + 8 * sub) * 4;
#pragma unroll
                for (int j = 0; j < 4; ++j)
                    R[sub][j] = *(const f32x4*)(xbase + (size_t)(cc0 + j) * 4096);
            }
        }
#pragma unroll
        for (int ks = 0; ks < 2; ++ks) {
            bf16x8 a0 = *(const bf16x8*)&mp[(32 * wid + q) * 256 + cc * 64 + ks * 32 + g * 8];
            bf16x8 a1 = *(const bf16x8*)&mp[(32 * wid + 16 + q) * 256 + cc * 64 + ks * 32 + g * 8];
#pragma unroll
            for (int ntl = 0; ntl < 16; ++ntl) {
                const int nn = ntl * 16 + q;
                bf16x8 bb = *(const bf16x8*)&xt[cur][(nn * 64 + ks * 32 + g * 8) ^ ((nn & 7) << 3)];
                acc[0][ntl] = mfma16(a0, bb, acc[0][ntl]);
                acc[1][ntl] = mfma16(a1, bb, acc[1][ntl]);
            }
        }
        if (ci < 3) {
#pragma unroll
            for (int sub = 0; sub < 2; ++sub)
#pragma unroll
                for (int j = 0; j < 4; ++j) {
                    const int n = n4 * 4 + j;
                    u16x4 pk;
                    pk[0] = f2bf(R[sub][0][j]); pk[1] = f2bf(R[sub][1][j]);
                    pk[2] = f2bf(R[sub][2][j]); pk[3] = f2bf(R[sub][3][j]);
                    *(u16x4*)&xt[cur ^ 1][(n * 64 + (c8 + 8 * sub) * 4) ^ ((n & 7) << 3)] = pk;
                }
        }
        __syncthreads();
    }

#pragma unroll
    for (int dt = 0; dt < 2; ++dt)
#pragma unroll
        for (int ntl = 0; ntl < 16; ++ntl)
#pragma unroll
            for (int rr = 0; rr < 4; ++rr) {
                const int d = 32 * wid + dt * 16 + 4 * g + rr;
                const int n = n0 + ntl * 16 + q;
                out[((size_t)b * 256 + d) * 4096 + n] = acc[dt][ntl][rr] + cp_l[d];
            }
}

// ---------------------------------------------------------------------------
extern "C" void kernel_launch(void* const* d_in, const int* in_sizes, int n_in,
                              void* d_out, int out_size, void* d_ws, size_t ws_size,
                              hipStream_t stream) {
    const float* x  = (const float*)d_in[0];
    const float* Wq = (const float*)d_in[1];
    const float* bq = (const float*)d_in[2];
    const float* Wk = (const float*)d_in[3];
    const float* bk = (const float*)d_in[4];
    const float* Wv = (const float*)d_in[5];
    const float* bv = (const float*)d_in[6];
    float* out = (float*)d_out;
    char* ws = (char*)d_ws;

    // layout (~69.4 MB; harness provides >=105MB, proven R6):
    //   [0, 64M):      Gpart bf16 (16 x 32 x 65536); dead after reduce ->
    //                  Tws [0,4M), Mws [4M,8M)
    //   [64M, 68M):    Gb bf16
    //   [68M, +1M):    rsp f32 (16 splits x 32 b x 512)
    //   then: cpv, WvT, Wqb, Wkb
    u16*   Gpart = (u16*)  (ws);
    u16*   Tws   = (u16*)  (ws);
    u16*   Mws   = (u16*)  (ws + 4194304);
    u16*   Gb    = (u16*)  (ws + 67108864);
    float* rsp   = (float*)(ws + 71303168);
    float* cpv   = (float*)(ws + 72351744);
    u16*   WvT   = (u16*)  (ws + 72384512);
    u16*   Wqb   = (u16*)  (ws + 72515584);
    u16*   Wkb   = (u16*)  (ws + 72646656);

    hipLaunchKernelGGL(k_wcvt3,    dim3(96),   dim3(256), 0, stream, Wq, Wk, Wv, Wqb, Wkb, WvT);
    hipLaunchKernelGGL(k_gram_b,   dim3(512),  dim3(512), 0, stream, x, Gpart, rsp);
    hipLaunchKernelGGL(k_reduce_b, dim3(1024), dim3(256), 0, stream, Gpart, Gb);
    hipLaunchKernelGGL(k_T,        dim3(256),  dim3(512), 0, stream, Gb, Wkb, Tws);
    hipLaunchKernelGGL(k_SWM,      dim3(128),  dim3(256), 0, stream,
                       Tws, rsp, Wq, Wqb, Wk, bq, bk, bv, WvT, Mws, cpv);
    hipLaunchKernelGGL(k_out,      dim3(512),  dim3(512), 0, stream, x, Mws, cpv, out);
}

// Round 13
// 174.788 us; speedup vs baseline: 1.2263x; 1.2263x over previous
//
#include <hip/hip_runtime.h>
#include <cstdint>
#include <cstddef>

// ---------------------------------------------------------------------------
// SelfAttentionLayer: x[32,256,4096] f32; Wq/Wk/Wv[256,256], bq/bk/bv[256]
//   G_b = X_b X_b^T,  r_b = X_b 1
//   S_b = Wq G Wk^T + (Wq r) bk^T + bq (Wk r)^T + N bq bk^T, scaled 1/64
//   W_b = softmax_rows(S_b);  M_b = W_b Wv;  c_b = W_b bv
//   out_b = M_b X_b + c_b 1^T
// R12 = R10 (measured best, 178.3us) + merged weight-convert (R11's one good
// piece). Gram reverted to 8 splits / grid 256 (R11's 16-split halved the
// per-block work -> prologue/flush fraction doubled, 50->100us: REVERTED).
// Ledger of failed structures (do not retry): R4 scattered small stores,
// R6 fused xbt, R7 16-wave blocks, R8 direct-global-MFMA k_out,
// R11 16-split gram.  Proven levers: traffic cuts on R5 skeleton, per-block
// chunk rotation (R10, -12us), non-atomic rowsum partials.
// ---------------------------------------------------------------------------

typedef float f32x4 __attribute__((ext_vector_type(4)));
typedef __bf16 bf16x8 __attribute__((ext_vector_type(8)));
typedef unsigned short u16;
typedef u16 u16x8 __attribute__((ext_vector_type(8)));
typedef u16 u16x4 __attribute__((ext_vector_type(4)));

__device__ __forceinline__ u16 f2bf(float f) {
    unsigned u = __builtin_bit_cast(unsigned, f);
    u += 0x7FFFu + ((u >> 16) & 1u);   // RNE
    return (u16)(u >> 16);
}
__device__ __forceinline__ float bf2f(u16 h) {
    unsigned u = ((unsigned)h) << 16;
    return __builtin_bit_cast(float, u);
}
__device__ __forceinline__ f32x4 mfma16(bf16x8 a, bf16x8 b, f32x4 c) {
    return __builtin_amdgcn_mfma_f32_16x16x32_bf16(a, b, c, 0, 0, 0);
}

// ---------------------------------------------------------------------------
// K0: merged weight converts. grid 96 x 256 thr.
//   blocks 0..31:  Wq -> Wqb (bf16)
//   blocks 32..63: Wk -> Wkb (bf16)
//   blocks 64..95: Wv -> WvT (bf16, transposed [c][e])
// ---------------------------------------------------------------------------
__global__ void k_wcvt3(const float* __restrict__ Wq, const float* __restrict__ Wk,
                        const float* __restrict__ Wv,
                        u16* __restrict__ Wqb, u16* __restrict__ Wkb,
                        u16* __restrict__ WvT) {
    const int m = blockIdx.x >> 5, sub = blockIdx.x & 31;
    if (m < 2) {
        const float* src = m == 0 ? Wq : Wk;
        u16* dst = m == 0 ? Wqb : Wkb;
        const int i = sub * 2048 + threadIdx.x * 8;
        f32x4 w0 = *(const f32x4*)(src + i);
        f32x4 w1 = *(const f32x4*)(src + i + 4);
        u16x8 pk;
        pk[0] = f2bf(w0[0]); pk[1] = f2bf(w0[1]); pk[2] = f2bf(w0[2]); pk[3] = f2bf(w0[3]);
        pk[4] = f2bf(w1[0]); pk[5] = f2bf(w1[1]); pk[6] = f2bf(w1[2]); pk[7] = f2bf(w1[3]);
        *(u16x8*)&dst[i] = pk;
    } else {
        const int eb = sub;            // e-base = eb*8
        const int c  = threadIdx.x;
        u16x8 pk;
#pragma unroll
        for (int j = 0; j < 8; ++j) pk[j] = f2bf(Wv[(eb * 8 + j) * 256 + c]);
        *(u16x8*)&WvT[c * 256 + eb * 8] = pk;
    }
}

// ---------------------------------------------------------------------------
// K1: pipelined Gram partials (R10-proven: 8 splits, grid 256, rotation).
// bf16 flush (safe q-in-column pattern); rowsums non-atomic to rsp.
// ---------------------------------------------------------------------------
__global__ __launch_bounds__(512, 2) void k_gram_b(const float* __restrict__ x,
                                                   u16* __restrict__ Gpart,
                                                   float* __restrict__ rsp) {
    __shared__ __align__(16) u16 lds[2][256 * 64];
    const int b = blockIdx.x >> 3, split = blockIdx.x & 7;
    const int rot = blockIdx.x & 7;
    const int t = threadIdx.x;
    const int lane = t & 63, wid = t >> 6;
    const int g = lane >> 4, q = lane & 15;

    f32x4 zero4 = {0.f, 0.f, 0.f, 0.f};
    f32x4 acc[2][16];
#pragma unroll
    for (int i = 0; i < 2; ++i)
#pragma unroll
        for (int j = 0; j < 16; ++j) acc[i][j] = zero4;

    const int c_st = t >> 1, half = t & 1;
    const int swz_w = (c_st & 7) << 3;
    const float* xp = x + ((size_t)b * 256 + c_st) * 4096 + split * 512 + half * 32;

    float s = 0.f;
    f32x4 R[8];
    // preload + stage chunk `rot`
#pragma unroll
    for (int j = 0; j < 8; ++j) R[j] = *(const f32x4*)(xp + rot * 64 + j * 4);
#pragma unroll
    for (int kk = 0; kk < 4; ++kk) {
        f32x4 w0 = R[2 * kk], w1 = R[2 * kk + 1];
        s += w0[0] + w0[1] + w0[2] + w0[3] + w1[0] + w1[1] + w1[2] + w1[3];
        u16x8 pk;
        pk[0] = f2bf(w0[0]); pk[1] = f2bf(w0[1]); pk[2] = f2bf(w0[2]); pk[3] = f2bf(w0[3]);
        pk[4] = f2bf(w1[0]); pk[5] = f2bf(w1[1]); pk[6] = f2bf(w1[2]); pk[7] = f2bf(w1[3]);
        *(u16x8*)&lds[0][(c_st * 64 + half * 32 + kk * 8) ^ swz_w] = pk;
    }
    __syncthreads();

    for (int nc = 0; nc < 8; ++nc) {
        const int cur = nc & 1;
        if (nc < 7) {
            const int nxt = (nc + 1 + rot) & 7;
#pragma unroll
            for (int j = 0; j < 8; ++j) R[j] = *(const f32x4*)(xp + nxt * 64 + j * 4);
        }
#pragma unroll
        for (int ks = 0; ks < 2; ++ks) {
            const int c0 = 32 * wid + q;
            const int c1 = c0 + 16;
            bf16x8 a0 = *(const bf16x8*)&lds[cur][(c0 * 64 + ks * 32 + g * 8) ^ ((c0 & 7) << 3)];
            bf16x8 a1 = *(const bf16x8*)&lds[cur][(c1 * 64 + ks * 32 + g * 8) ^ ((c1 & 7) << 3)];
#pragma unroll
            for (int et = 0; et < 16; ++et) {
                const int c2 = et * 16 + q;
                bf16x8 bb = *(const bf16x8*)&lds[cur][(c2 * 64 + ks * 32 + g * 8) ^ ((c2 & 7) << 3)];
                acc[0][et] = mfma16(a0, bb, acc[0][et]);
                acc[1][et] = mfma16(a1, bb, acc[1][et]);
            }
        }
        if (nc < 7) {
#pragma unroll
            for (int kk = 0; kk < 4; ++kk) {
                f32x4 w0 = R[2 * kk], w1 = R[2 * kk + 1];
                s += w0[0] + w0[1] + w0[2] + w0[3] + w1[0] + w1[1] + w1[2] + w1[3];
                u16x8 pk;
                pk[0] = f2bf(w0[0]); pk[1] = f2bf(w0[1]); pk[2] = f2bf(w0[2]); pk[3] = f2bf(w0[3]);
                pk[4] = f2bf(w1[0]); pk[5] = f2bf(w1[1]); pk[6] = f2bf(w1[2]); pk[7] = f2bf(w1[3]);
                *(u16x8*)&lds[cur ^ 1][(c_st * 64 + half * 32 + kk * 8) ^ swz_w] = pk;
            }
        }
        __syncthreads();
    }

    // non-atomic rowsum partial (block owns its slice)
    rsp[(size_t)(split * 32 + b) * 512 + t] = s;

    // bf16 partial flush, safe q-in-column pattern (R7/R9-proven)
    u16* gp = Gpart + (size_t)(split * 32 + b) * 65536;
#pragma unroll
    for (int dt = 0; dt < 2; ++dt)
#pragma unroll
        for (int et = 0; et < 16; ++et)
#pragma unroll
            for (int rr = 0; rr < 4; ++rr) {
                const int cc = 32 * wid + dt * 16 + 4 * g + rr;
                gp[cc * 256 + et * 16 + q] = f2bf(acc[dt][et][rr]);
            }
}

// ---------------------------------------------------------------------------
// K2: Gb[j] = bf16( sum over 8 bf16 partials ).  grid 1024 x 256.
// ---------------------------------------------------------------------------
__global__ void k_reduce_b(const u16* __restrict__ Gpart, u16* __restrict__ Gb) {
    const size_t j = ((size_t)blockIdx.x * 256 + threadIdx.x) * 8;
    float s[8];
#pragma unroll
    for (int i = 0; i < 8; ++i) s[i] = 0.f;
#pragma unroll
    for (int sp = 0; sp < 8; ++sp) {
        u16x8 v = *(const u16x8*)(Gpart + (size_t)sp * 2097152 + j);
#pragma unroll
        for (int i = 0; i < 8; ++i) s[i] += bf2f(v[i]);
    }
    u16x8 pk;
#pragma unroll
    for (int i = 0; i < 8; ++i) pk[i] = f2bf(s[i]);
    *(u16x8*)&Gb[j] = pk;
}

// ---------------------------------------------------------------------------
// K3: T^T[e][c] = sum_c' G[c,c'] Wk[e,c'].  grid = 32 b x 8 e-tiles of 32.
// ---------------------------------------------------------------------------
__global__ __launch_bounds__(512, 4) void k_T(const u16* __restrict__ Gb,
                                              const u16* __restrict__ Wkb,
                                              u16* __restrict__ Tws) {
    const int b = blockIdx.x >> 3, ebase = (blockIdx.x & 7) * 32;
    const int t = threadIdx.x;
    const int lane = t & 63, wid = t >> 6;
    const int g = lane >> 4, q = lane & 15;

    f32x4 zero4 = {0.f, 0.f, 0.f, 0.f};
    f32x4 acc[2][2];
#pragma unroll
    for (int i = 0; i < 2; ++i)
#pragma unroll
        for (int j = 0; j < 2; ++j) acc[i][j] = zero4;

    const u16* gp = Gb + (size_t)b * 65536;
#pragma unroll
    for (int ks = 0; ks < 8; ++ks) {
        bf16x8 a0 = *(const bf16x8*)&gp[(32 * wid + q) * 256 + ks * 32 + g * 8];
        bf16x8 a1 = *(const bf16x8*)&gp[(32 * wid + 16 + q) * 256 + ks * 32 + g * 8];
        bf16x8 b0 = *(const bf16x8*)&Wkb[(ebase + q) * 256 + ks * 32 + g * 8];
        bf16x8 b1 = *(const bf16x8*)&Wkb[(ebase + 16 + q) * 256 + ks * 32 + g * 8];
        acc[0][0] = mfma16(a0, b0, acc[0][0]);
        acc[0][1] = mfma16(a0, b1, acc[0][1]);
        acc[1][0] = mfma16(a1, b0, acc[1][0]);
        acc[1][1] = mfma16(a1, b1, acc[1][1]);
    }
#pragma unroll
    for (int dt = 0; dt < 2; ++dt)
#pragma unroll
        for (int etl = 0; etl < 2; ++etl) {
            const int e = ebase + etl * 16 + q;
            const int cb = 32 * wid + dt * 16 + 4 * g;
            u16x4 pk;
            pk[0] = f2bf(acc[dt][etl][0]); pk[1] = f2bf(acc[dt][etl][1]);
            pk[2] = f2bf(acc[dt][etl][2]); pk[3] = f2bf(acc[dt][etl][3]);
            *(u16x4*)&Tws[((size_t)b * 256 + e) * 256 + cb] = pk;
        }
}

// ---------------------------------------------------------------------------
// K4: S^T -> softmax -> M^T.  grid = 32 b x 4 d-tiles of 64.  256 thr.
// Rowsum r_ summed from 8 non-atomic split partials (rsp).
// ---------------------------------------------------------------------------
__global__ __launch_bounds__(256, 2) void k_SWM(
    const u16* __restrict__ Tws, const float* __restrict__ rsp,
    const float* __restrict__ Wq, const u16* __restrict__ Wqb,
    const float* __restrict__ Wk,
    const float* __restrict__ bqv, const float* __restrict__ bkv,
    const float* __restrict__ bvv,
    const u16* __restrict__ WvT, u16* __restrict__ Mws, float* __restrict__ cpv) {
    __shared__ __align__(16) u16 Wlds[64 * 256];
    __shared__ float r_[256], v_[256], bk_[256], bv_[256], u_[64], bq_[64];
    const int b = blockIdx.x >> 2, dbase = (blockIdx.x & 3) * 64;
    const int t = threadIdx.x;
    const int lane = t & 63, wid = t >> 6;
    const int g = lane >> 4, q = lane & 15;

    {
        float sr = 0.f;
#pragma unroll
        for (int sp = 0; sp < 8; ++sp) {
            const float* rp = rsp + (size_t)(sp * 32 + b) * 512;
            sr += rp[2 * t] + rp[2 * t + 1];
        }
        r_[t] = sr;
    }
    bk_[t] = bkv[t];
    bv_[t] = bvv[t];
    if (t < 64) bq_[t] = bqv[dbase + t];
    __syncthreads();

    {
        float s = 0.f; const float* wp = Wk + (size_t)t * 256;
#pragma unroll 4
        for (int c = 0; c < 256; c += 4) {
            f32x4 w = *(const f32x4*)(wp + c);
            f32x4 rr = *(const f32x4*)(&r_[c]);
            s += w[0] * rr[0] + w[1] * rr[1] + w[2] * rr[2] + w[3] * rr[3];
        }
        v_[t] = s;
    }
    if (t < 64) {
        float s = 0.f; const float* wp = Wq + (size_t)(dbase + t) * 256;
#pragma unroll 4
        for (int c = 0; c < 256; c += 4) {
            f32x4 w = *(const f32x4*)(wp + c);
            f32x4 rr = *(const f32x4*)(&r_[c]);
            s += w[0] * rr[0] + w[1] * rr[1] + w[2] * rr[2] + w[3] * rr[3];
        }
        u_[t] = s;
    }
    __syncthreads();

    f32x4 zero4 = {0.f, 0.f, 0.f, 0.f};
    f32x4 acc[16];
#pragma unroll
    for (int j = 0; j < 16; ++j) acc[j] = zero4;

    const u16* tp = Tws + (size_t)b * 65536;
    const int d_l = wid * 16 + q;
#pragma unroll 2
    for (int ks = 0; ks < 8; ++ks) {
        bf16x8 bb = *(const bf16x8*)&Wqb[(dbase + d_l) * 256 + ks * 32 + g * 8];
#pragma unroll
        for (int et = 0; et < 16; ++et) {
            bf16x8 aa = *(const bf16x8*)&tp[(et * 16 + q) * 256 + ks * 32 + g * 8];
            acc[et] = mfma16(aa, bb, acc[et]);
        }
    }

    {
        const float ud = u_[d_l], bqd = bq_[d_l];
        float m = -3.4e38f;
#pragma unroll
        for (int et = 0; et < 16; ++et)
#pragma unroll
            for (int rr = 0; rr < 4; ++rr) {
                const int e = et * 16 + 4 * g + rr;
                float s = (acc[et][rr] + ud * bk_[e] + bqd * v_[e] + 4096.f * bqd * bk_[e]) * 0.015625f;
                acc[et][rr] = s;
                m = fmaxf(m, s);
            }
        m = fmaxf(m, __shfl_xor(m, 16));
        m = fmaxf(m, __shfl_xor(m, 32));
        float lsum = 0.f;
#pragma unroll
        for (int et = 0; et < 16; ++et)
#pragma unroll
            for (int rr = 0; rr < 4; ++rr) {
                float p = __expf(acc[et][rr] - m);
                acc[et][rr] = p;
                lsum += p;
            }
        lsum += __shfl_xor(lsum, 16);
        lsum += __shfl_xor(lsum, 32);
        const float inv = 1.f / lsum;
        float cp = 0.f;
#pragma unroll
        for (int et = 0; et < 16; ++et)
#pragma unroll
            for (int rr = 0; rr < 4; ++rr) {
                const int e = et * 16 + 4 * g + rr;
                float w = acc[et][rr] * inv;
                acc[et][rr] = w;
                cp += w * bv_[e];
            }
        cp += __shfl_xor(cp, 16);
        cp += __shfl_xor(cp, 32);
        if (g == 0) cpv[b * 256 + dbase + d_l] = cp;
    }

#pragma unroll
    for (int et = 0; et < 16; ++et) {
        u16x4 pk;
        pk[0] = f2bf(acc[et][0]); pk[1] = f2bf(acc[et][1]);
        pk[2] = f2bf(acc[et][2]); pk[3] = f2bf(acc[et][3]);
        *(u16x4*)&Wlds[(d_l * 256 + et * 16 + 4 * g) ^ ((d_l & 7) << 3)] = pk;
    }
    __syncthreads();

    f32x4 acc2[4][4];
#pragma unroll
    for (int i = 0; i < 4; ++i)
#pragma unroll
        for (int j = 0; j < 4; ++j) acc2[i][j] = zero4;

#pragma unroll 2
    for (int ks = 0; ks < 8; ++ks) {
        bf16x8 afr[4], bfr[4];
#pragma unroll
        for (int ct = 0; ct < 4; ++ct)
            afr[ct] = *(const bf16x8*)&WvT[(64 * wid + ct * 16 + q) * 256 + ks * 32 + g * 8];
#pragma unroll
        for (int j = 0; j < 4; ++j) {
            const int dl = j * 16 + q;
            bfr[j] = *(const bf16x8*)&Wlds[(dl * 256 + ks * 32 + g * 8) ^ ((dl & 7) << 3)];
        }
#pragma unroll
        for (int ct = 0; ct < 4; ++ct)
#pragma unroll
            for (int j = 0; j < 4; ++j)
                acc2[ct][j] = mfma16(afr[ct], bfr[j], acc2[ct][j]);
    }
#pragma unroll
    for (int ct = 0; ct < 4; ++ct)
#pragma unroll
        for (int j = 0; j < 4; ++j) {
            const int d = dbase + j * 16 + q;
            const int cb = 64 * wid + ct * 16 + 4 * g;
            u16x4 pk;
            pk[0] = f2bf(acc2[ct][j][0]); pk[1] = f2bf(acc2[ct][j][1]);
            pk[2] = f2bf(acc2[ct][j][2]); pk[3] = f2bf(acc2[ct][j][3]);
            *(u16x4*)&Mws[((size_t)b * 256 + d) * 256 + cb] = pk;
        }
}

// ---------------------------------------------------------------------------
// K5: out = M X + c 1^T.  grid = 32 b x 16 n-tiles, 512 thr.  R10 structure
// (rotated c-chunk order, plain stores).
// ---------------------------------------------------------------------------
__global__ __launch_bounds__(512, 2) void k_out(const float* __restrict__ x,
                                                const u16* __restrict__ Mws,
                                                const float* __restrict__ cpv,
                                                float* __restrict__ out) {
    __shared__ __align__(16) u16 xt[2][256 * 64];
    __shared__ float cp_l[256];
    const int b = blockIdx.x >> 4, nt = blockIdx.x & 15;
    const int rot = blockIdx.x & 3;
    const int n0 = nt * 256;
    const int t = threadIdx.x;
    const int lane = t & 63, wid = t >> 6;
    const int g = lane >> 4, q = lane & 15;

    if (t < 256) cp_l[t] = cpv[b * 256 + t];

    f32x4 zero4 = {0.f, 0.f, 0.f, 0.f};
    f32x4 acc[2][16];
#pragma unroll
    for (int i = 0; i < 2; ++i)
#pragma unroll
        for (int j = 0; j < 16; ++j) acc[i][j] = zero4;

    const int c8 = t & 7;
    const int n4 = t >> 3;
    const float* xbase = x + (size_t)b * 256 * 4096 + n0 + n4 * 4;
    const u16* mp = Mws + (size_t)b * 65536;

    f32x4 R[2][4];
    // preload + stage chunk `rot`
#pragma unroll
    for (int sub = 0; sub < 2; ++sub) {
        const int cc0 = rot * 64 + (c8 + 8 * sub) * 4;
#pragma unroll
        for (int j = 0; j < 4; ++j)
            R[sub][j] = *(const f32x4*)(xbase + (size_t)(cc0 + j) * 4096);
    }
#pragma unroll
    for (int sub = 0; sub < 2; ++sub)
#pragma unroll
        for (int j = 0; j < 4; ++j) {
            const int n = n4 * 4 + j;
            u16x4 pk;
            pk[0] = f2bf(R[sub][0][j]); pk[1] = f2bf(R[sub][1][j]);
            pk[2] = f2bf(R[sub][2][j]); pk[3] = f2bf(R[sub][3][j]);
            *(u16x4*)&xt[0][(n * 64 + (c8 + 8 * sub) * 4) ^ ((n & 7) << 3)] = pk;
        }
    __syncthreads();

    for (int ci = 0; ci < 4; ++ci) {
        const int cur = ci & 1;
        const int cc = (ci + rot) & 3;          // chunk being computed
        if (ci < 3) {
            const int nxt = (ci + 1 + rot) & 3; // chunk being prefetched
#pragma unroll
            for (int sub = 0; sub < 2; ++sub) {
                const int cc0 = nxt * 64 + (c8 + 8 * sub) * 4;
#pragma unroll
                for (int j = 0; j < 4; ++j)
                    R[sub][j] = *(const f32x4*)(xbase + (size_t)(cc0 + j) * 4096);
            }
        }
#pragma unroll
        for (int ks = 0; ks < 2; ++ks) {
            bf16x8 a0 = *(const bf16x8*)&mp[(32 * wid + q) * 256 + cc * 64 + ks * 32 + g * 8];
            bf16x8 a1 = *(const bf16x8*)&mp[(32 * wid + 16 + q) * 256 + cc * 64 + ks * 32 + g * 8];
#pragma unroll
            for (int ntl = 0; ntl < 16; ++ntl) {
                const int nn = ntl * 16 + q;
                bf16x8 bb = *(const bf16x8*)&xt[cur][(nn * 64 + ks * 32 + g * 8) ^ ((nn & 7) << 3)];
                acc[0][ntl] = mfma16(a0, bb, acc[0][ntl]);
                acc[1][ntl] = mfma16(a1, bb, acc[1][ntl]);
            }
        }
        if (ci < 3) {
#pragma unroll
            for (int sub = 0; sub < 2; ++sub)
#pragma unroll
                for (int j = 0; j < 4; ++j) {
                    const int n = n4 * 4 + j;
                    u16x4 pk;
                    pk[0] = f2bf(R[sub][0][j]); pk[1] = f2bf(R[sub][1][j]);
                    pk[2] = f2bf(R[sub][2][j]); pk[3] = f2bf(R[sub][3][j]);
                    *(u16x4*)&xt[cur ^ 1][(n * 64 + (c8 + 8 * sub) * 4) ^ ((n & 7) << 3)] = pk;
                }
        }
        __syncthreads();
    }

#pragma unroll
    for (int dt = 0; dt < 2; ++dt)
#pragma unroll
        for (int ntl = 0; ntl < 16; ++ntl)
#pragma unroll
            for (int rr = 0; rr < 4; ++rr) {
                const int d = 32 * wid + dt * 16 + 4 * g + rr;
                const int n = n0 + ntl * 16 + q;
                out[((size_t)b * 256 + d) * 4096 + n] = acc[dt][ntl][rr] + cp_l[d];
            }
}

// ---------------------------------------------------------------------------
extern "C" void kernel_launch(void* const* d_in, const int* in_sizes, int n_in,
                              void* d_out, int out_size, void* d_ws, size_t ws_size,
                              hipStream_t stream) {
    const float* x  = (const float*)d_in[0];
    const float* Wq = (const float*)d_in[1];
    const float* bq = (const float*)d_in[2];
    const float* Wk = (const float*)d_in[3];
    const float* bk = (const float*)d_in[4];
    const float* Wv = (const float*)d_in[5];
    const float* bv = (const float*)d_in[6];
    float* out = (float*)d_out;
    char* ws = (char*)d_ws;

    // layout (~39 MB; harness provides >=105MB, proven R6):
    //   [0, 32M):      Gpart bf16 (8 x 32 x 65536); dead after reduce ->
    //                  Tws [0,4M), Mws [4M,8M)
    //   [32M, 36M):    Gb bf16
    //   [36M, +512K):  rsp f32 (8 splits x 32 b x 512)
    //   then: cpv, WvT, Wqb, Wkb
    u16*   Gpart = (u16*)  (ws);
    u16*   Tws   = (u16*)  (ws);
    u16*   Mws   = (u16*)  (ws + 4194304);
    u16*   Gb    = (u16*)  (ws + 33554432);
    float* rsp   = (float*)(ws + 37748736);
    float* cpv   = (float*)(ws + 38273024);
    u16*   WvT   = (u16*)  (ws + 38305792);
    u16*   Wqb   = (u16*)  (ws + 38436864);
    u16*   Wkb   = (u16*)  (ws + 38567936);

    hipLaunchKernelGGL(k_wcvt3,    dim3(96),   dim3(256), 0, stream, Wq, Wk, Wv, Wqb, Wkb, WvT);
    hipLaunchKernelGGL(k_gram_b,   dim3(256),  dim3(512), 0, stream, x, Gpart, rsp);
    hipLaunchKernelGGL(k_reduce_b, dim3(1024), dim3(256), 0, stream, Gpart, Gb);
    hipLaunchKernelGGL(k_T,        dim3(256),  dim3(512), 0, stream, Gb, Wkb, Tws);
    hipLaunchKernelGGL(k_SWM,      dim3(128),  dim3(256), 0, stream,
                       Tws, rsp, Wq, Wqb, Wk, bq, bk, bv, WvT, Mws, cpv);
    hipLaunchKernelGGL(k_out,      dim3(512),  dim3(512), 0, stream, x, Mws, cpv, out);
}